// Round 9
// baseline (4593.701 us; speedup 1.0000x reference)
//
#include <hip/hip_runtime.h>
#include <hip/hip_fp16.h>
#include <hip/hip_bf16.h>

typedef __attribute__((ext_vector_type(8))) short bf16x8;
typedef __attribute__((ext_vector_type(4))) float f32x4;

__device__ __forceinline__ short f2bf(float f) {
    unsigned u = __builtin_bit_cast(unsigned, f);
    unsigned r = (u + 0x7FFFu + ((u >> 16) & 1u)) >> 16;
    return (short)r;
}
__device__ __forceinline__ float fast_rcp(float x) {
    return __builtin_amdgcn_rcpf(x);
}
__device__ __forceinline__ float fast_exp(float x) {
    return __builtin_amdgcn_exp2f(x * 1.4426950408889634f);
}

// ---------------------------------------------------------------------------
// Prep: transpose + convert weights to bf16.
// ---------------------------------------------------------------------------
__global__ __launch_bounds__(256) void prep_kernel(
    const float* __restrict__ kf, const float* __restrict__ kb,
    const float* __restrict__ rf, const float* __restrict__ rb,
    short* __restrict__ kT, short* __restrict__ rTf, short* __restrict__ rTb)
{
    int idx = blockIdx.x * 256 + threadIdx.x;   // 0 .. 1536*256-1
    int n = idx >> 8;
    int k = idx & 255;
    const float* src = (n < 768) ? kf : kb;
    int nn = (n < 768) ? n : (n - 768);
    kT[idx] = f2bf(src[k * 768 + nn]);
    if (n < 768) {
        rTf[idx] = f2bf(rf[k * 768 + n]);
        rTb[idx] = f2bf(rb[k * 768 + n]);
    }
}

// ---------------------------------------------------------------------------
// Projection GEMM: xw = x@kernel + bias0 (+bias1 folded for z,r).
// Output layout PERMUTED for the gru kernel's per-lane register loads:
//   per (dir): region16 (64MB): [bg(4)][t(1024)][wt(16)][lane(64)][8 halves]
//              region8  (32MB, at +64MB): [bg][t][wt][lane][4 halves]
// ---------------------------------------------------------------------------
__global__ __launch_bounds__(256) void proj_kernel(
    const float* __restrict__ x, const short* __restrict__ kT,
    const float* __restrict__ bias_f, const float* __restrict__ bias_b,
    char* __restrict__ xwp_f, char* __restrict__ xwp_b)
{
    __shared__ short lA[64][264];
    __shared__ short lB[128][264];

    const int tid = threadIdx.x;
    const int m0 = blockIdx.x * 64;
    const int n0 = blockIdx.y * 128;

    const int b_blk  = m0 >> 10;
    const int bg     = b_blk >> 4;
    const int rowg   = b_blk & 15;
    const int hi_t   = rowg >> 2;
    const int i_t    = rowg & 3;
    const int tbase  = m0 & 1023;

#pragma unroll
    for (int rep = 0; rep < 16; ++rep) {
        int lin = rep * 256 + tid;
        int r = lin >> 6;
        int c4 = lin & 63;
        float4 v = *(const float4*)(x + (size_t)(m0 + r) * 256 + c4 * 4);
        short4 s;
        s.x = f2bf(v.x); s.y = f2bf(v.y); s.z = f2bf(v.z); s.w = f2bf(v.w);
        *(short4*)&lA[r][c4 * 4] = s;
    }
#pragma unroll
    for (int rep = 0; rep < 16; ++rep) {
        int lin = rep * 256 + tid;
        int r = lin >> 5;
        int c8 = lin & 31;
        uint4 v = *(const uint4*)(kT + (size_t)(n0 + r) * 256 + c8 * 8);
        *(uint4*)&lB[r][c8 * 8] = v;
    }
    __syncthreads();

    const int w = tid >> 6, l = tid & 63;
    const int l15 = l & 15, hi = l >> 4;

    bf16x8 a[8];
#pragma unroll
    for (int kt = 0; kt < 8; ++kt)
        a[kt] = *(const bf16x8*)&lA[w * 16 + l15][kt * 32 + hi * 8];

#pragma unroll
    for (int j = 0; j < 8; ++j) {
        f32x4 acc = {0.f, 0.f, 0.f, 0.f};
#pragma unroll
        for (int kt = 0; kt < 8; ++kt) {
            bf16x8 b = *(const bf16x8*)&lB[j * 16 + l15][kt * 32 + hi * 8];
            acc = __builtin_amdgcn_mfma_f32_16x16x32_bf16(a[kt], b, acc, 0, 0, 0);
        }
        int ng = n0 + j * 16 + l15;
        int dirb = ng >= 768;
        int nn = ng - (dirb ? 768 : 0);
        const float* bias = dirb ? bias_b : bias_f;
        float badd = bias[nn] + ((nn < 512) ? bias[768 + nn] : 0.f);
        char* basep = dirb ? xwp_b : xwp_f;

        int g   = nn >> 8;           // 0=z, 1=r, 2=h
        int cg2 = nn & 255;
        int wt  = cg2 >> 4;
        int lane_t = hi_t * 16 + (cg2 & 15);

#pragma unroll
        for (int i = 0; i < 4; ++i) {
            int t = tbase + w * 16 + hi * 4 + i;
            unsigned short hv = __builtin_bit_cast(unsigned short,
                                    __float2half(acc[i] + badd));
            if (g < 2) {
                *(unsigned short*)(basep + ((size_t)bg << 24) + ((size_t)t << 14)
                                   + (wt << 10) + (lane_t << 4) + ((g * 4 + i_t) << 1)) = hv;
            } else {
                *(unsigned short*)(basep + 67108864u + ((size_t)bg << 23) + ((size_t)t << 13)
                                   + (wt << 9) + (lane_t << 3) + (i_t << 1)) = hv;
            }
        }
    }
}

// ---------------------------------------------------------------------------
// Recurrence, COLUMN-SPLIT across CU pairs.
// 16 blocks x 512 threads: bid = half*8 + dir*4 + bg. Block computes z/r/h~
// for its 128 h-columns (c0 = half*128), full K=256. Per step:
//   MFMA own-half K-frags (h from own LDS, A-frag layout, double-buffered)
//   -> spin partner flag -> load remote h (4x dwordx4 from partner's
//   published [row16][col128] bf16 slot) -> MFMA remote K-frags -> gates.
// h(s) lives in slot[s&1]; flags monotonic (=s+1 after publishing h(s+1));
// release/acquire AGENT-scope atomics; flags zeroed per launch by memset.
// All 24 B-fragments register-resident (512thr -> 256 VGPR budget).
// ---------------------------------------------------------------------------
#define GRU_STEP(PR, PW, RSLOT, PSLOT)                                       \
  {                                                                          \
    uint4  xv16 = *(const uint4*)xp16;  xp16 += step16;                      \
    uint2  xv8  = *(const uint2*)xp8;   xp8  += step8;                       \
    f32x4 az = {0.f,0.f,0.f,0.f}, ar = {0.f,0.f,0.f,0.f},                    \
          ah = {0.f,0.f,0.f,0.f};                                            \
    _Pragma("unroll") for (int ko = 0; ko < 4; ++ko) {                       \
      bf16x8 aq = *(const bf16x8*)((const char*)hfrag + (PR)*4096            \
                                   + ko * 1024 + l * 16);                    \
      az = __builtin_amdgcn_mfma_f32_16x16x32_bf16(aq, BzO[ko], az, 0,0,0);  \
      ar = __builtin_amdgcn_mfma_f32_16x16x32_bf16(aq, BrO[ko], ar, 0,0,0);  \
      ah = __builtin_amdgcn_mfma_f32_16x16x32_bf16(aq, BhO[ko], ah, 0,0,0);  \
    }                                                                        \
    if (s > 0) {                                                             \
      while (__hip_atomic_load(flagp, __ATOMIC_ACQUIRE,                      \
                               __HIP_MEMORY_SCOPE_AGENT) < s)                \
        __builtin_amdgcn_s_sleep(1);                                         \
      const char* rb = pubR + (RSLOT)*4096 + l15 * 256 + hi * 16;            \
      bf16x8 ra0 = *(const bf16x8*)(rb);                                     \
      bf16x8 ra1 = *(const bf16x8*)(rb + 64);                                \
      bf16x8 ra2 = *(const bf16x8*)(rb + 128);                               \
      bf16x8 ra3 = *(const bf16x8*)(rb + 192);                               \
      az = __builtin_amdgcn_mfma_f32_16x16x32_bf16(ra0, BzR[0], az, 0,0,0);  \
      ar = __builtin_amdgcn_mfma_f32_16x16x32_bf16(ra0, BrR[0], ar, 0,0,0);  \
      ah = __builtin_amdgcn_mfma_f32_16x16x32_bf16(ra0, BhR[0], ah, 0,0,0);  \
      az = __builtin_amdgcn_mfma_f32_16x16x32_bf16(ra1, BzR[1], az, 0,0,0);  \
      ar = __builtin_amdgcn_mfma_f32_16x16x32_bf16(ra1, BrR[1], ar, 0,0,0);  \
      ah = __builtin_amdgcn_mfma_f32_16x16x32_bf16(ra1, BhR[1], ah, 0,0,0);  \
      az = __builtin_amdgcn_mfma_f32_16x16x32_bf16(ra2, BzR[2], az, 0,0,0);  \
      ar = __builtin_amdgcn_mfma_f32_16x16x32_bf16(ra2, BrR[2], ar, 0,0,0);  \
      ah = __builtin_amdgcn_mfma_f32_16x16x32_bf16(ra2, BhR[2], ah, 0,0,0);  \
      az = __builtin_amdgcn_mfma_f32_16x16x32_bf16(ra3, BzR[3], az, 0,0,0);  \
      ar = __builtin_amdgcn_mfma_f32_16x16x32_bf16(ra3, BrR[3], ar, 0,0,0);  \
      ah = __builtin_amdgcn_mfma_f32_16x16x32_bf16(ra3, BhR[3], ah, 0,0,0);  \
    }                                                                        \
    const __half* hx  = (const __half*)&xv16;                                \
    const __half* hx8 = (const __half*)&xv8;                                 \
    float hn[4];                                                             \
    char* pubw = pubMe + (PSLOT)*4096 + (hi * 4) * 256 + col_rel * 2;        \
    _Pragma("unroll") for (int i = 0; i < 4; ++i) {                          \
      float zi  = fast_rcp(1.f + fast_exp(-(__half2float(hx[i]) + az[i])));  \
      float rri = fast_rcp(1.f + fast_exp(-(__half2float(hx[4+i]) + ar[i])));\
      float pre = __half2float(hx8[i]) + rri * (ah[i] + b1h);                \
      float sg  = fast_rcp(1.f + fast_exp(-2.f * pre));                      \
      float hh  = 2.f * sg - 1.f;                                            \
      float h2  = hh + zi * (hold[i] - hh);                                  \
      hold[i] = h2;  hn[i] = h2;                                             \
      opbase[i * 524288] = h2;                                               \
      *(short*)(pubw + i * 256) = f2bf(h2);                                  \
    }                                                                        \
    unsigned pk0, pk1;                                                       \
    asm("v_cvt_pk_bf16_f32 %0, %1, %2" : "=v"(pk0) : "v"(hn[0]), "v"(hn[1]));\
    asm("v_cvt_pk_bf16_f32 %0, %1, %2" : "=v"(pk1) : "v"(hn[2]), "v"(hn[3]));\
    {                                                                        \
      char* hb = (char*)hfrag + (PW)*4096 + wb;                              \
      *(short*)(hb)      = (short)(pk0 & 0xffff);                            \
      *(short*)(hb + 16) = (short)(pk0 >> 16);                               \
      *(short*)(hb + 32) = (short)(pk1 & 0xffff);                            \
      *(short*)(hb + 48) = (short)(pk1 >> 16);                               \
    }                                                                        \
    opbase += ostep;                                                         \
    __syncthreads();           /* drains vmcnt (publish) + lgkm (hfrag) */   \
    if (tid == 0)                                                            \
      __hip_atomic_store(flagMe, s + 1, __ATOMIC_RELEASE,                    \
                         __HIP_MEMORY_SCOPE_AGENT);                          \
    ++s;                                                                     \
  }

__global__ __launch_bounds__(512) void gru_kernel(
    const char* __restrict__ xwp_f, const char* __restrict__ xwp_b,
    const short* __restrict__ recT_f, const short* __restrict__ recT_b,
    const float* __restrict__ bias_f, const float* __restrict__ bias_b,
    char* __restrict__ hpub, int* __restrict__ flags,
    float* __restrict__ out)
{
    __shared__ short hfrag[2][4][64][8];      // own-half h, A-frag layout, 8KB

    const int tid = threadIdx.x;
    const int w = tid >> 6, l = tid & 63;     // w in 0..7
    const int l15 = l & 15, hi = l >> 4;
    const int bid  = blockIdx.x;
    const int half = bid >> 3;
    const int dir  = (bid >> 2) & 1;
    const int bg   = bid & 3;
    const int b0   = bg * 16;
    const int c0   = half * 128;
    const int pbid = bid ^ 8;

    const char*  xwp  = dir ? xwp_b  : xwp_f;
    const short* recT = dir ? recT_b : recT_f;
    const float* bias = dir ? bias_b : bias_f;

    const int col_rel = w * 16 + l15;          // 0..127
    const int cg = c0 + col_rel;               // global h column
    const float b1h = bias[768 + 512 + cg];

    // zero both hfrag buffers (8KB = 512 x int4)
    ((int4*)hfrag)[tid] = make_int4(0, 0, 0, 0);

    // B fragments: own-half K-frags and remote-half K-frags, all in registers
    const char* recTc = (const char*)recT;
    unsigned offz = (((unsigned)(cg)       * 256u) + hi * 8u) * 2u;
    unsigned offr = (((unsigned)(256 + cg) * 256u) + hi * 8u) * 2u;
    unsigned offh = (((unsigned)(512 + cg) * 256u) + hi * 8u) * 2u;
    const int ktlo = half * 4;                 // own K-frags (cols c0..c0+127)
    const int ktro = 4 - ktlo;                 // remote K-frag base
    bf16x8 BzO[4], BrO[4], BhO[4], BzR[4], BrR[4], BhR[4];
#pragma unroll
    for (int k = 0; k < 4; ++k) {
        BzO[k] = *(const bf16x8*)(recTc + offz + (ktlo + k) * 64);
        BrO[k] = *(const bf16x8*)(recTc + offr + (ktlo + k) * 64);
        BhO[k] = *(const bf16x8*)(recTc + offh + (ktlo + k) * 64);
        BzR[k] = *(const bf16x8*)(recTc + offz + (ktro + k) * 64);
        BrR[k] = *(const bf16x8*)(recTc + offr + (ktro + k) * 64);
        BhR[k] = *(const bf16x8*)(recTc + offh + (ktro + k) * 64);
    }

    // xw per-lane streaming pointers (permuted layout; wt = half*8 + w)
    const int t0 = dir ? 1023 : 0;
    const long step16 = dir ? -16384 : 16384;
    const long step8  = dir ? -8192  : 8192;
    const int wt = half * 8 + w;
    const char* xp16 = xwp + ((size_t)bg << 24) + ((size_t)t0 << 14)
                       + (wt << 10) + (l << 4);
    const char* xp8  = xwp + 67108864u + ((size_t)bg << 23) + ((size_t)t0 << 13)
                       + (wt << 9) + (l << 3);

    // out: rows b0+hi*4+i, column dir*256+cg, time t
    const long ostep = dir ? -512 : 512;
    float* opbase = out + (size_t)(b0 + hi * 4) * 524288 + (size_t)t0 * 512
                    + (size_t)dir * 256 + cg;

    // h-write byte offset within an hfrag slot (A-frag position of (row, col_rel))
    const unsigned wb = (unsigned)(col_rel >> 5) * 1024u
                      + (unsigned)((2 * w + (l15 >> 3)) & 3) * 256u
                      + (unsigned)hi * 64u + (unsigned)(l15 & 7) * 2u;

    // exchange pointers
    char* pubMe = hpub + (size_t)bid * 8192;
    const char* pubR = hpub + (size_t)pbid * 8192;
    int* flagMe = flags + bid;
    const int* flagp = flags + pbid;

    f32x4 hold = {0.f, 0.f, 0.f, 0.f};
    int s = 0;
    __syncthreads();      // hfrag zeros visible

    for (int su = 0; su < 512; ++su) {
        GRU_STEP(0, 1, 0, 1)   // even s: read hfrag0 + remote slot0, write hfrag1 + pub slot1
        GRU_STEP(1, 0, 1, 0)   // odd  s: read hfrag1 + remote slot1, write hfrag0 + pub slot0
    }
}

// ---------------------------------------------------------------------------
extern "C" void kernel_launch(void* const* d_in, const int* in_sizes, int n_in,
                              void* d_out, int out_size, void* d_ws, size_t ws_size,
                              hipStream_t stream) {
    const float* x   = (const float*)d_in[0];
    const float* kf  = (const float*)d_in[1];
    const float* rf  = (const float*)d_in[2];
    const float* bf_ = (const float*)d_in[3];
    const float* kb  = (const float*)d_in[4];
    const float* rb  = (const float*)d_in[5];
    const float* bb_ = (const float*)d_in[6];

    char* ws = (char*)d_ws;
    char* xwp_f = ws;                                 // 96MB permuted xw (fwd)
    char* xwp_b = ws + 100663296;                     // 96MB permuted xw (bwd)
    short* rTf  = (short*)(ws + 201326592);           // 768*256 bf16
    short* rTb  = (short*)(ws + 201719808);
    short* kT   = (short*)(ws + 202113024);           // 1536*256 bf16
    char*  hpub = ws + 202899456;                     // 16 x 2 x 4KB = 128KB
    int*   flags = (int*)(ws + 203030528);            // 16 ints
    float* out  = (float*)d_out;

    hipMemsetAsync(flags, 0, 64, stream);
    hipLaunchKernelGGL(prep_kernel, dim3(1536), dim3(256), 0, stream,
                       kf, kb, rf, rb, kT, rTf, rTb);
    hipLaunchKernelGGL(proj_kernel, dim3(1024, 12), dim3(256), 0, stream,
                       x, kT, bf_, bb_, xwp_f, xwp_b);
    hipLaunchKernelGGL(gru_kernel, dim3(16), dim3(512), 0, stream,
                       xwp_f, xwp_b, rTf, rTb, bf_, bb_, hpub, flags, out);
}

// Round 10
// 1938.724 us; speedup vs baseline: 2.3694x; 2.3694x over previous
//
#include <hip/hip_runtime.h>
#include <hip/hip_fp16.h>
#include <hip/hip_bf16.h>

typedef __attribute__((ext_vector_type(8))) short bf16x8;
typedef __attribute__((ext_vector_type(4))) float f32x4;

__device__ __forceinline__ short f2bf(float f) {
    unsigned u = __builtin_bit_cast(unsigned, f);
    unsigned r = (u + 0x7FFFu + ((u >> 16) & 1u)) >> 16;
    return (short)r;
}
__device__ __forceinline__ float fast_rcp(float x) {
    return __builtin_amdgcn_rcpf(x);
}
__device__ __forceinline__ float fast_exp(float x) {
    return __builtin_amdgcn_exp2f(x * 1.4426950408889634f);
}

// ---------------------------------------------------------------------------
// Prep: transpose + convert weights to bf16.
// ---------------------------------------------------------------------------
__global__ __launch_bounds__(256) void prep_kernel(
    const float* __restrict__ kf, const float* __restrict__ kb,
    const float* __restrict__ rf, const float* __restrict__ rb,
    short* __restrict__ kT, short* __restrict__ rTf, short* __restrict__ rTb)
{
    int idx = blockIdx.x * 256 + threadIdx.x;   // 0 .. 1536*256-1
    int n = idx >> 8;
    int k = idx & 255;
    const float* src = (n < 768) ? kf : kb;
    int nn = (n < 768) ? n : (n - 768);
    kT[idx] = f2bf(src[k * 768 + nn]);
    if (n < 768) {
        rTf[idx] = f2bf(rf[k * 768 + n]);
        rTb[idx] = f2bf(rb[k * 768 + n]);
    }
}

// ---------------------------------------------------------------------------
// Projection GEMM: xw = x@kernel + bias0 (+bias1 folded for z,r).
// Output layout PERMUTED for the gru kernel's per-lane register loads:
//   per (dir): region16 (64MB): [bg(4)][t(1024)][wt(16)][lane(64)][8 halves]
//              region8  (32MB, at +64MB): [bg][t][wt][lane][4 halves]
// ---------------------------------------------------------------------------
__global__ __launch_bounds__(256) void proj_kernel(
    const float* __restrict__ x, const short* __restrict__ kT,
    const float* __restrict__ bias_f, const float* __restrict__ bias_b,
    char* __restrict__ xwp_f, char* __restrict__ xwp_b)
{
    __shared__ short lA[64][264];
    __shared__ short lB[128][264];

    const int tid = threadIdx.x;
    const int m0 = blockIdx.x * 64;
    const int n0 = blockIdx.y * 128;

    const int b_blk  = m0 >> 10;
    const int bg     = b_blk >> 4;
    const int rowg   = b_blk & 15;
    const int hi_t   = rowg >> 2;
    const int i_t    = rowg & 3;
    const int tbase  = m0 & 1023;

#pragma unroll
    for (int rep = 0; rep < 16; ++rep) {
        int lin = rep * 256 + tid;
        int r = lin >> 6;
        int c4 = lin & 63;
        float4 v = *(const float4*)(x + (size_t)(m0 + r) * 256 + c4 * 4);
        short4 s;
        s.x = f2bf(v.x); s.y = f2bf(v.y); s.z = f2bf(v.z); s.w = f2bf(v.w);
        *(short4*)&lA[r][c4 * 4] = s;
    }
#pragma unroll
    for (int rep = 0; rep < 16; ++rep) {
        int lin = rep * 256 + tid;
        int r = lin >> 5;
        int c8 = lin & 31;
        uint4 v = *(const uint4*)(kT + (size_t)(n0 + r) * 256 + c8 * 8);
        *(uint4*)&lB[r][c8 * 8] = v;
    }
    __syncthreads();

    const int w = tid >> 6, l = tid & 63;
    const int l15 = l & 15, hi = l >> 4;

    bf16x8 a[8];
#pragma unroll
    for (int kt = 0; kt < 8; ++kt)
        a[kt] = *(const bf16x8*)&lA[w * 16 + l15][kt * 32 + hi * 8];

#pragma unroll
    for (int j = 0; j < 8; ++j) {
        f32x4 acc = {0.f, 0.f, 0.f, 0.f};
#pragma unroll
        for (int kt = 0; kt < 8; ++kt) {
            bf16x8 b = *(const bf16x8*)&lB[j * 16 + l15][kt * 32 + hi * 8];
            acc = __builtin_amdgcn_mfma_f32_16x16x32_bf16(a[kt], b, acc, 0, 0, 0);
        }
        int ng = n0 + j * 16 + l15;
        int dirb = ng >= 768;
        int nn = ng - (dirb ? 768 : 0);
        const float* bias = dirb ? bias_b : bias_f;
        float badd = bias[nn] + ((nn < 512) ? bias[768 + nn] : 0.f);
        char* basep = dirb ? xwp_b : xwp_f;

        int g   = nn >> 8;           // 0=z, 1=r, 2=h
        int cg2 = nn & 255;
        int wt  = cg2 >> 4;
        int lane_t = hi_t * 16 + (cg2 & 15);

#pragma unroll
        for (int i = 0; i < 4; ++i) {
            int t = tbase + w * 16 + hi * 4 + i;
            unsigned short hv = __builtin_bit_cast(unsigned short,
                                    __float2half(acc[i] + badd));
            if (g < 2) {
                *(unsigned short*)(basep + ((size_t)bg << 24) + ((size_t)t << 14)
                                   + (wt << 10) + (lane_t << 4) + ((g * 4 + i_t) << 1)) = hv;
            } else {
                *(unsigned short*)(basep + 67108864u + ((size_t)bg << 23) + ((size_t)t << 13)
                                   + (wt << 9) + (lane_t << 3) + (i_t << 1)) = hv;
            }
        }
    }
}

// ---------------------------------------------------------------------------
// Recurrence: 8 blocks (2 dirs x 4 groups of 16 batch rows), 512 threads =
// 8 waves. Wave w owns TWO 16-col tiles: cols [32w,32w+16) and [32w+16,32w+32).
//  - A-frag LDS reads HALVED vs 16-wave: 8 b128/wave/step, shared by both
//    tiles (A is column-independent). 64 reads/CU/step.
//  - 42 of 48 B-frags register-resident (168 regs; 512thr -> 256 budget);
//    6 (Bh tails kt=5..7, both tiles) in LDS per-lane layout (48 reads/step).
//  - h state in MFMA A-FRAGMENT layout, double-buffered.
//  - xw per-lane 2x dwordx4 + 2x dwordx2 (second tile at +1024/+512 imm).
//  - gates x2 tiles; h->bf16 via v_cvt_pk_bf16_f32.
//  - ONE lgkm-only raw barrier per step.
// ---------------------------------------------------------------------------
#define MFMA_BF16(A, B, C) __builtin_amdgcn_mfma_f32_16x16x32_bf16(A, B, C, 0, 0, 0)

#define GRU_GATES(AZ, AR, AH, HX, HX8, HOLD, OPOFF, WBOFF, B1H)              \
    _Pragma("unroll") for (int i = 0; i < 4; ++i) {                          \
      float zi  = fast_rcp(1.f + fast_exp(-(__half2float(HX[i]) + AZ[i])));  \
      float rri = fast_rcp(1.f + fast_exp(-(__half2float(HX[4+i]) + AR[i])));\
      float pre = __half2float(HX8[i]) + rri * (AH[i] + B1H);                \
      float sg  = fast_rcp(1.f + fast_exp(-2.f * pre));                      \
      float hh  = 2.f * sg - 1.f;                                            \
      float h2  = hh + zi * (HOLD[i] - hh);                                  \
      HOLD[i] = h2;  hn[i] = h2;                                             \
      opbase[(OPOFF) + i * 524288] = h2;                                     \
    }                                                                        \
    asm("v_cvt_pk_bf16_f32 %0, %1, %2" : "=v"(pk0) : "v"(hn[0]), "v"(hn[1]));\
    asm("v_cvt_pk_bf16_f32 %0, %1, %2" : "=v"(pk1) : "v"(hn[2]), "v"(hn[3]));\
    {                                                                        \
      char* hb = hwBase + (WBOFF);                                           \
      *(short*)(hb)      = (short)(pk0 & 0xffff);                            \
      *(short*)(hb + 16) = (short)(pk0 >> 16);                               \
      *(short*)(hb + 32) = (short)(pk1 & 0xffff);                            \
      *(short*)(hb + 48) = (short)(pk1 >> 16);                               \
    }

#define GRU_STEP(PR, PW)                                                     \
  {                                                                          \
    uint4 xv16a = *(const uint4*)xp16;                                       \
    uint4 xv16b = *(const uint4*)(xp16 + 1024);  xp16 += step16;             \
    uint2 xv8a  = *(const uint2*)xp8;                                        \
    uint2 xv8b  = *(const uint2*)(xp8 + 512);    xp8  += step8;              \
    unsigned bb = 0;                                                         \
    asm volatile("" : "+v"(bb));      /* defeat cross-step LDS-read hoist */ \
    f32x4 az0={0.f,0.f,0.f,0.f}, ar0={0.f,0.f,0.f,0.f}, ah0={0.f,0.f,0.f,0.f};\
    f32x4 az1={0.f,0.f,0.f,0.f}, ar1={0.f,0.f,0.f,0.f}, ah1={0.f,0.f,0.f,0.f};\
    _Pragma("unroll") for (int kt = 0; kt < 8; ++kt) {                       \
      bf16x8 aq = *(const bf16x8*)((const char*)hfrag + (PR)*8192            \
                                   + kt * 1024 + l * 16);                    \
      bf16x8 bh0v, bh1v;                                                     \
      if (kt < 5) { bh0v = Bh0[kt]; bh1v = Bh1[kt]; }                        \
      else {                                                                 \
        bh0v = *(const bf16x8*)(bfragc + bb + (kt - 5) * 8192                \
                                + w * 1024 + l * 16);                        \
        bh1v = *(const bf16x8*)(bfragc + bb + 24576 + (kt - 5) * 8192        \
                                + w * 1024 + l * 16);                        \
      }                                                                      \
      az0 = MFMA_BF16(aq, Bz0[kt], az0);                                     \
      ar0 = MFMA_BF16(aq, Br0[kt], ar0);                                     \
      ah0 = MFMA_BF16(aq, bh0v,    ah0);                                     \
      az1 = MFMA_BF16(aq, Bz1[kt], az1);                                     \
      ar1 = MFMA_BF16(aq, Br1[kt], ar1);                                     \
      ah1 = MFMA_BF16(aq, bh1v,    ah1);                                     \
    }                                                                        \
    const __half* hxa  = (const __half*)&xv16a;                              \
    const __half* hx8a = (const __half*)&xv8a;                               \
    const __half* hxb  = (const __half*)&xv16b;                              \
    const __half* hx8b = (const __half*)&xv8b;                               \
    float hn[4];                                                             \
    unsigned pk0, pk1;                                                       \
    char* hwBase = (char*)hfrag + (PW)*8192;                                 \
    GRU_GATES(az0, ar0, ah0, hxa, hx8a, hold0, 0,  wb,       b1h0)           \
    GRU_GATES(az1, ar1, ah1, hxb, hx8b, hold1, 16, wb + 512, b1h1)           \
    opbase += ostep;                                                         \
    asm volatile("s_waitcnt lgkmcnt(0)\n\ts_barrier" ::: "memory");          \
  }

__global__ __launch_bounds__(512) void gru_kernel(
    const char* __restrict__ xwp_f, const char* __restrict__ xwp_b,
    const short* __restrict__ recT_f, const short* __restrict__ recT_b,
    const float* __restrict__ bias_f, const float* __restrict__ bias_b,
    float* __restrict__ out)
{
    __shared__ short hfrag[2][8][64][8];       // h in A-frag layout, 16KB
    __shared__ short bfrag[2][3][8][64][8];    // Bh tails (2 tiles x kt5..7), 48KB

    const int tid = threadIdx.x;
    const int w = tid >> 6, l = tid & 63;      // w in 0..7
    const int l15 = l & 15, hi = l >> 4;
    const int dir = blockIdx.x >> 2;
    const int bg  = blockIdx.x & 3;
    const int b0  = bg * 16;

    const char*  xwp  = dir ? xwp_b  : xwp_f;
    const short* recT = dir ? recT_b : recT_f;
    const float* bias = dir ? bias_b : bias_f;

    const int cg0 = w * 32 + l15;              // first owned column
    // second owned column = cg0 + 16
    const float b1h0 = bias[768 + 512 + cg0];
    const float b1h1 = bias[768 + 512 + cg0 + 16];

    // zero both hfrag buffers (16KB = 1024 x int4; 512 threads x 2)
    ((int4*)hfrag)[tid]       = make_int4(0, 0, 0, 0);
    ((int4*)hfrag)[tid + 512] = make_int4(0, 0, 0, 0);

    // B fragments: 42 resident (Bz/Br both tiles, Bh kt0..4 both tiles),
    // 6 to LDS (Bh kt5..7 both tiles)
    const char* recTc = (const char*)recT;
    const char* bfragc = (const char*)bfrag;
    unsigned offz = (((unsigned)(cg0)       * 256u) + hi * 8u) * 2u;
    unsigned offr = (((unsigned)(256 + cg0) * 256u) + hi * 8u) * 2u;
    unsigned offh = (((unsigned)(512 + cg0) * 256u) + hi * 8u) * 2u;
    bf16x8 Bz0[8], Br0[8], Bz1[8], Br1[8], Bh0[5], Bh1[5];
#pragma unroll
    for (int kt = 0; kt < 8; ++kt) {
        Bz0[kt] = *(const bf16x8*)(recTc + offz + kt * 64);
        Br0[kt] = *(const bf16x8*)(recTc + offr + kt * 64);
        Bz1[kt] = *(const bf16x8*)(recTc + offz + 8192 + kt * 64);
        Br1[kt] = *(const bf16x8*)(recTc + offr + 8192 + kt * 64);
    }
#pragma unroll
    for (int kt = 0; kt < 5; ++kt) {
        Bh0[kt] = *(const bf16x8*)(recTc + offh + kt * 64);
        Bh1[kt] = *(const bf16x8*)(recTc + offh + 8192 + kt * 64);
    }
#pragma unroll
    for (int kt = 5; kt < 8; ++kt) {
        bf16x8 t0v = *(const bf16x8*)(recTc + offh + kt * 64);
        bf16x8 t1v = *(const bf16x8*)(recTc + offh + 8192 + kt * 64);
        *(bf16x8*)((char*)bfrag + (kt - 5) * 8192 + w * 1024 + l * 16) = t0v;
        *(bf16x8*)((char*)bfrag + 24576 + (kt - 5) * 8192 + w * 1024 + l * 16) = t1v;
    }

    // xw per-lane streaming pointers (permuted layout; wt = 2w / 2w+1)
    const int t0 = dir ? 1023 : 0;
    const long step16 = dir ? -16384 : 16384;
    const long step8  = dir ? -8192  : 8192;
    const char* xp16 = xwp + ((size_t)bg << 24) + ((size_t)t0 << 14)
                       + ((2 * w) << 10) + (l << 4);
    const char* xp8  = xwp + 67108864u + ((size_t)bg << 23) + ((size_t)t0 << 13)
                       + ((2 * w) << 9) + (l << 3);

    // out: rows b0+hi*4+i, columns dir*256+cg0 and +16, time t
    const long ostep = dir ? -512 : 512;
    float* opbase = out + (size_t)(b0 + hi * 4) * 524288 + (size_t)t0 * 512
                    + (size_t)dir * 256 + cg0;

    // h-write byte offset in hfrag buf for (row hi*4, col cg):
    //   f(c) = (c>>5)*1024 + ((c>>3)&3)*256 + (hi*4)*16 + (c&7)*2 ; +i*16 per row
    // cg1 = cg0+16 -> f(cg1) = f(cg0) + 512
    const unsigned wb = (unsigned)(cg0 >> 5) * 1024u
                      + (unsigned)((cg0 >> 3) & 3) * 256u
                      + (unsigned)(hi * 4) * 16u + (unsigned)(cg0 & 7) * 2u;

    f32x4 hold0 = {0.f, 0.f, 0.f, 0.f};
    f32x4 hold1 = {0.f, 0.f, 0.f, 0.f};
    __syncthreads();      // hfrag zeros + bfrag writes visible

    for (int su = 0; su < 512; ++su) {
        GRU_STEP(0, 1)
        GRU_STEP(1, 0)
    }
}

// ---------------------------------------------------------------------------
extern "C" void kernel_launch(void* const* d_in, const int* in_sizes, int n_in,
                              void* d_out, int out_size, void* d_ws, size_t ws_size,
                              hipStream_t stream) {
    const float* x   = (const float*)d_in[0];
    const float* kf  = (const float*)d_in[1];
    const float* rf  = (const float*)d_in[2];
    const float* bf_ = (const float*)d_in[3];
    const float* kb  = (const float*)d_in[4];
    const float* rb  = (const float*)d_in[5];
    const float* bb_ = (const float*)d_in[6];

    char* ws = (char*)d_ws;
    char* xwp_f = ws;                                 // 96MB permuted xw (fwd)
    char* xwp_b = ws + 100663296;                     // 96MB permuted xw (bwd)
    short* rTf  = (short*)(ws + 201326592);           // 768*256 bf16
    short* rTb  = (short*)(ws + 201719808);
    short* kT   = (short*)(ws + 202113024);           // 1536*256 bf16
    float* out  = (float*)d_out;

    hipLaunchKernelGGL(prep_kernel, dim3(1536), dim3(256), 0, stream,
                       kf, kb, rf, rb, kT, rTf, rTb);
    hipLaunchKernelGGL(proj_kernel, dim3(1024, 12), dim3(256), 0, stream,
                       x, kT, bf_, bb_, xwp_f, xwp_b);
    hipLaunchKernelGGL(gru_kernel, dim3(8), dim3(512), 0, stream,
                       xwp_f, xwp_b, rTf, rTb, bf_, bb_, out);
}